// Round 5
// baseline (131.225 us; speedup 1.0000x reference)
//
#include <hip/hip_runtime.h>
#include <hip/hip_fp8.h>

#define NV 4
#define NB 2048
#define ND 512
#define NN 8192
// sim = cos/TEMP, TEMP=0.5 -> scale 2.0

typedef int int8v __attribute__((ext_vector_type(8)));
typedef int int4v __attribute__((ext_vector_type(4)));
typedef float floatx4 __attribute__((ext_vector_type(4)));
#define SCALE1 0x7F7F7F7Fu  // E8M0 bytes 127 -> 2^0 = 1.0

// ---------------- normalize: x[N,D] f32 -> xn[N,D] fp8 e4m3 (unit rows) ----
__global__ __launch_bounds__(256) void normalize_k(const float* __restrict__ x,
                                                   unsigned char* __restrict__ xn,
                                                   float* __restrict__ sumexp,
                                                   float* __restrict__ out) {
  if (threadIdx.x < 4) sumexp[blockIdx.x * 4 + threadIdx.x] = 0.0f;
  if (blockIdx.x == 0 && threadIdx.x == 0) out[0] = 0.0f;

  const int row = blockIdx.x * 4 + (threadIdx.x >> 6);  // one wave per row
  const int l = threadIdx.x & 63;                        // lane: cols [8l, 8l+8)
  const float4* xr = (const float4*)(x + (size_t)row * ND);
  float4 v0 = xr[l * 2 + 0];
  float4 v1 = xr[l * 2 + 1];
  float ss = v0.x * v0.x + v0.y * v0.y + v0.z * v0.z + v0.w * v0.w +
             v1.x * v1.x + v1.y * v1.y + v1.z * v1.z + v1.w * v1.w;
#pragma unroll
  for (int off = 32; off > 0; off >>= 1) ss += __shfl_xor(ss, off, 64);
  const float inv = 1.0f / fmaxf(sqrtf(ss), 1e-8f);
  union { unsigned char b[8]; uint2 u; } pk;
  pk.b[0] = __hip_fp8_e4m3(v0.x * inv).__x;
  pk.b[1] = __hip_fp8_e4m3(v0.y * inv).__x;
  pk.b[2] = __hip_fp8_e4m3(v0.z * inv).__x;
  pk.b[3] = __hip_fp8_e4m3(v0.w * inv).__x;
  pk.b[4] = __hip_fp8_e4m3(v1.x * inv).__x;
  pk.b[5] = __hip_fp8_e4m3(v1.y * inv).__x;
  pk.b[6] = __hip_fp8_e4m3(v1.z * inv).__x;
  pk.b[7] = __hip_fp8_e4m3(v1.w * inv).__x;
  *(uint2*)(xn + (size_t)row * ND + l * 8) = pk.u;
}

// ---------------- fused sim GEMM + exp/mask epilogue, triangular, fp8-MX ----
// R12: FULL-K-IN-LDS, zero K-loop synchronization.
// Post-mortems R7/R8/R11: 2-barrier 128² = 48.2, 2-barrier 256² = 51.5,
// counted-vmcnt phases = 58.6 µs — all share per-K-step barrier lockstep at
// <=1.3 blocks/CU, and all sit at MfmaUtil 11-13% (MFMA-busy == 6.4-7.6 µs
// floor). K=512 is tiny: a 128² tile's ENTIRE A+B is 2*128*512 B = 128 KiB
// -> fits LDS whole. So: stage once (32 gll/wave, deeply pipelined, one
// vmcnt(0) drain via a single __syncthreads), then a barrier-free compute
// stream: 4 unrolled K-steps x {16 ds_read_b128 + 16 MFMA}/wave — compiler
// schedules with fine lgkmcnt, no phase lockstep, no further barriers.
// 256 thr / 4 waves (1/SIMD): reg budget 512 -> full kt-unroll (~350 regs
// worst case incl 64 acc) fits without spill [verify: WRITE_SIZE ~3.5 MB].
// 2080 blocks -> 8.1 rounds/CU, tail negligible. XCD swizzle (2080 = 8*260).
//
// LDS layout (512 B rows now): LDS[R][chunk c] = G[R][c ^ (R&7)], chunks are
// 16 B. gll writes linearly (1 KiB per gll = 2 rows; lane l -> row +l>>5,
// chunk l&31) with pre-swizzled global source chunk (l&31)^(R&7), where
// R&7 = (2i + (l>>5))&7 (period 4 in slab i). Read side identical to the
// verified R7/R8 scheme: fo = (kt*8 + ((2q+j)^s))*16, s = row&7 = m&7.
__global__ __launch_bounds__(256, 1) void sim_k(const unsigned char* __restrict__ xn,
                                                float* __restrict__ sumexp,
                                                float* __restrict__ pos) {
  __shared__ unsigned char As[128 * 512];  // 64 KiB, full-K A tile
  __shared__ unsigned char Bs[128 * 512];  // 64 KiB, full-K B tile
  const int tid = threadIdx.x;
  const int l = tid & 63;
  const int m = l & 15, q = l >> 4, s = l & 7;
  const int w = tid >> 6;
  const int wr = w >> 1, wc = w & 1;  // wave tile: 64x64 at (wr*64, wc*64)

  // XCD-aware swizzle: 2080 = 8*260, bijective.
  const int bid = (blockIdx.x & 7) * 260 + (blockIdx.x >> 3);
  // triangular decode over 64 tiles: bid -> (rt, ct), rt <= ct
  int rt = (int)((129.0f - sqrtf(16641.0f - 8.0f * (float)bid)) * 0.5f);
  rt = rt < 0 ? 0 : (rt > 63 ? 63 : rt);
  while (rt > 0 && (rt * 64 - rt * (rt - 1) / 2) > bid) --rt;
  while (rt < 63 && ((rt + 1) * 64 - (rt + 1) * rt / 2) <= bid) ++rt;
  const int ct = rt + (bid - (rt * 64 - rt * (rt - 1) / 2));
  const bool diag = (rt == ct);

  const unsigned char* gA = xn + (size_t)rt * 128 * ND;
  const unsigned char* gB = xn + (size_t)ct * 128 * ND;

#define GLL16(gp, lp)                                                        \
  __builtin_amdgcn_global_load_lds(                                          \
      (const __attribute__((address_space(1))) void*)(gp),                   \
      (__attribute__((address_space(3))) void*)(lp), 16, 0, 0)

  // ---- stage both full-K tiles: 128 gll total, 32 per wave ----
  // slab g covers rows 2g,2g+1 (1 KiB). Waves 0-1 -> A, waves 2-3 -> B.
  {
    int swz[4];
#pragma unroll
    for (int j = 0; j < 4; ++j)
      swz[j] = ((l & 31) ^ ((2 * j + (l >> 5)) & 7)) * 16;
    const size_t lrow = (size_t)(l >> 5) * 512;  // lane's row parity offset
    if (w < 2) {
      const int g0 = w * 32;
#pragma unroll
      for (int i = 0; i < 32; ++i)
        GLL16(gA + lrow + (size_t)(g0 + i) * 1024 + swz[i & 3],
              As + (g0 + i) * 1024);
    } else {
      const int g0 = (w - 2) * 32;
#pragma unroll
      for (int i = 0; i < 32; ++i)
        GLL16(gB + lrow + (size_t)(g0 + i) * 1024 + swz[i & 3],
              Bs + (g0 + i) * 1024);
    }
  }
  __syncthreads();  // single drain: vmcnt(0) + barrier — the only sync

  // ---- barrier-free compute: 4 K-steps, 16 reads + 16 MFMA each ----
  const int fo0 = ((2 * q + 0) ^ s) * 16;
  const int fo1 = ((2 * q + 1) ^ s) * 16;
  floatx4 acc[4][4] = {};

#define LDFRAG(dst, base, row, kt)                                           \
  do {                                                                       \
    const unsigned char* p_ = (base) + (size_t)(row) * 512 + (kt) * 128;     \
    dst = __builtin_shufflevector(*(const int4v*)(p_ + fo0),                 \
                                  *(const int4v*)(p_ + fo1),                 \
                                  0, 1, 2, 3, 4, 5, 6, 7);                   \
  } while (0)

#pragma unroll
  for (int kt = 0; kt < 4; ++kt) {
    int8v af0, af1, af2, af3, bf0, bf1, bf2, bf3;
    LDFRAG(af0, As, wr * 64 + 0 * 16 + m, kt);
    LDFRAG(af1, As, wr * 64 + 1 * 16 + m, kt);
    LDFRAG(af2, As, wr * 64 + 2 * 16 + m, kt);
    LDFRAG(af3, As, wr * 64 + 3 * 16 + m, kt);
    LDFRAG(bf0, Bs, wc * 64 + 0 * 16 + m, kt);
    LDFRAG(bf1, Bs, wc * 64 + 1 * 16 + m, kt);
    LDFRAG(bf2, Bs, wc * 64 + 2 * 16 + m, kt);
    LDFRAG(bf3, Bs, wc * 64 + 3 * 16 + m, kt);
#define MFMA_ROW(mt, afv)                                                    \
  acc[mt][0] = __builtin_amdgcn_mfma_scale_f32_16x16x128_f8f6f4(             \
      afv, bf0, acc[mt][0], 0, 0, 0, SCALE1, 0, SCALE1);                     \
  acc[mt][1] = __builtin_amdgcn_mfma_scale_f32_16x16x128_f8f6f4(             \
      afv, bf1, acc[mt][1], 0, 0, 0, SCALE1, 0, SCALE1);                     \
  acc[mt][2] = __builtin_amdgcn_mfma_scale_f32_16x16x128_f8f6f4(             \
      afv, bf2, acc[mt][2], 0, 0, 0, SCALE1, 0, SCALE1);                     \
  acc[mt][3] = __builtin_amdgcn_mfma_scale_f32_16x16x128_f8f6f4(             \
      afv, bf3, acc[mt][3], 0, 0, 0, SCALE1, 0, SCALE1)
    MFMA_ROW(0, af0);
    MFMA_ROW(1, af1);
    MFMA_ROW(2, af2);
    MFMA_ROW(3, af3);
#undef MFMA_ROW
  }

  // epilogue: s = 2*acc; masked cols ((c-r)%B==0) store pos, skip sums.
  // Row sums always; col sums + pos mirror only on off-diagonal tiles.
  const int r0 = rt * 128 + wr * 64;
  const int c0 = ct * 128 + wc * 64;
  float cs[4] = {0.f, 0.f, 0.f, 0.f};  // per-nt column partials (this lane's q)
#pragma unroll
  for (int mt = 0; mt < 4; ++mt) {
    float rs[4] = {0.f, 0.f, 0.f, 0.f};
#pragma unroll
    for (int nt = 0; nt < 4; ++nt) {
      const int c = c0 + nt * 16 + m;  // C layout: col = lane&15
#pragma unroll
      for (int reg = 0; reg < 4; ++reg) {
        const int r = r0 + mt * 16 + q * 4 + reg;  // row = quad*4 + reg
        const float sv = acc[mt][nt][reg] * 2.0f;
        if (((c - r) & (NB - 1)) == 0) {
          pos[r * NV + (c >> 11)] = sv;  // includes j==i (unused later)
          if (!diag) pos[c * NV + (r >> 11)] = sv;
        } else {
          const float e = __expf(sv);
          rs[reg] += e;
          cs[nt] += e;
        }
      }
    }
    // reduce rows across the 16-lane column dimension (m)
#pragma unroll
    for (int off = 1; off < 16; off <<= 1) {
#pragma unroll
      for (int reg = 0; reg < 4; ++reg) rs[reg] += __shfl_xor(rs[reg], off, 64);
    }
    if (m < 4) atomicAdd(&sumexp[r0 + mt * 16 + q * 4 + m], rs[m]);
  }
  if (!diag) {
    // reduce cols across the 4-quad row dimension (q)
#pragma unroll
    for (int nt = 0; nt < 4; ++nt) {
      cs[nt] += __shfl_xor(cs[nt], 16, 64);
      cs[nt] += __shfl_xor(cs[nt], 32, 64);
    }
    if (q == 0) {
#pragma unroll
      for (int nt = 0; nt < 4; ++nt)
        atomicAdd(&sumexp[c0 + nt * 16 + m], cs[nt]);
    }
  }
}

// ---------------- finalize: scalar loss -------------------------------------
__global__ __launch_bounds__(256) void finalize_k(
    const float* __restrict__ sumexp, const float* __restrict__ pos,
    float* __restrict__ out) {
  const int r = blockIdx.x * 256 + threadIdx.x;
  const float se = sumexp[r];
  const int i = r >> 11;  // view index
  float local = 0.0f;
#pragma unroll
  for (int j = 0; j < NV; ++j) {
    if (j == i) continue;
    const float p = pos[r * NV + j];
    local += logf(__expf(p) + se) - p;  // logaddexp(pos, lse_neg) - pos
  }
  local *= (1.0f / NB);
#pragma unroll
  for (int off = 32; off > 0; off >>= 1) local += __shfl_xor(local, off, 64);
  if ((threadIdx.x & 63) == 0) atomicAdd(out, local);
}

extern "C" void kernel_launch(void* const* d_in, const int* in_sizes, int n_in,
                              void* d_out, int out_size, void* d_ws,
                              size_t ws_size, hipStream_t stream) {
  const float* x = (const float*)d_in[0];
  float* out = (float*)d_out;
  char* ws = (char*)d_ws;
  unsigned char* xn = (unsigned char*)ws;                 // 4 MB fp8
  float* sumexp = (float*)(ws + (size_t)NN * ND);         // 32 KB
  float* pos = (float*)(ws + (size_t)NN * ND + NN * 4);   // 128 KB

  normalize_k<<<NN / 4, 256, 0, stream>>>(x, xn, sumexp, out);
  sim_k<<<64 * 65 / 2, 256, 0, stream>>>(xn, sumexp, pos);
  finalize_k<<<NN / 256, 256, 0, stream>>>(sumexp, pos, out);
}